// Round 15
// baseline (115.411 us; speedup 1.0000x reference)
//
#include <hip/hip_runtime.h>

#define DIM 128     // D_IN == D_OUT == 128
#define CAP 64      // per-node neighbor capacity (Poisson(16); P(deg>64) ~ 1e-18/node)
#define CHUNK 4096  // edges per bin block (512 threads, 8 edges/thread)

typedef __attribute__((ext_vector_type(8))) short bf16x8;
typedef __attribute__((ext_vector_type(4))) float f32x4;
typedef __attribute__((ext_vector_type(2))) float f32x2;

__device__ __forceinline__ unsigned short f2b(float f) {  // f32 -> bf16 RNE (data has no NaN/Inf)
  unsigned int u = __float_as_uint(f);
  return (unsigned short)((u + 0x7FFFu + ((u >> 16) & 1u)) >> 16);
}
__device__ __forceinline__ float blo(unsigned int v) { return __uint_as_float(v << 16); }
__device__ __forceinline__ float bhi(unsigned int v) { return __uint_as_float(v & 0xFFFF0000u); }

// Launch 1 (EXACT best-measured r10-proposal config, 96.3us total):
//  blocks [0, G): one-pass GEMM. W (f32 [128][384]) staged ONCE per block into
//    LDS bf16 [n=384][k=128], XOR-swizzled -> ds_read_b128 ~2-way (free).
//    Each wave sweeps 32-row macro-tiles (one B sweep feeds TWO 16-row tiles).
//    g1 = feat@W1^T+bias (bf16), g2 = feat@W2^T (fp8 e4m3), g3 = feat@W3^T (fp8).
//  blocks [G, G+nblk): LDS counting-sort binning of a 4096-edge chunk by
//    node>>8, both dirs. Coalesced writes only; no global atomics.
__global__ __launch_bounds__(512) void k_gemmbin(
    const float* __restrict__ feat, const float* __restrict__ W,
    const float* __restrict__ bias,
    const int* __restrict__ src, const int* __restrict__ dst,
    unsigned short* __restrict__ g1b, unsigned char* __restrict__ g2f8,
    unsigned char* __restrict__ g3f8,
    unsigned int* __restrict__ scrF, unsigned int* __restrict__ scrB,
    int* __restrict__ offsF, int* __restrict__ offsB,
    int N, int E, int G, int nblk) {
  __shared__ __align__(16) unsigned char smem[98304];   // 96KB union
  const int t = threadIdx.x;

  if ((int)blockIdx.x < G) {                 // ---- GEMM part ----
    for (int i = t; i < 12288; i += 512) {   // stage W -> LDS bf16, swizzled
      int flat = i * 4;
      int o = flat / 384;                    // W row = output col within section
      int kk = flat - o * 384;
      int n = (kk >> 7) * 128 + o;           // virtual concat col
      int k0 = kk & 127;
      float4 v = *(const float4*)(W + flat);
      ushort4 u; u.x = f2b(v.x); u.y = f2b(v.y); u.z = f2b(v.z); u.w = f2b(v.w);
      *(ushort4*)(smem + ((n * 256 + k0 * 2) ^ ((n & 7) << 4))) = u;
    }
    __syncthreads();

    const int wave = t >> 6, lane = t & 63;
    const int lr = lane & 15, lk = lane >> 4;
    float bv[8];
    #pragma unroll
    for (int i = 0; i < 8; ++i) bv[i] = bias[i * 16 + lr];

    const int MT = (N + 31) >> 5;            // 1563 macro-tiles of 32 rows
    const int TW = G * 8;
    for (int mt = blockIdx.x * 8 + wave; mt < MT; mt += TW) {
      const int m0 = mt * 32;
      const bool two = (m0 + 16 < N);
      bf16x8 a0[4], a1[4];
      #pragma unroll
      for (int kc = 0; kc < 4; ++kc) {       // feat f32 -> bf16 fragments
        const float* p = feat + (size_t)(m0 + lr) * DIM + kc * 32 + lk * 8;
        float4 u = *(const float4*)p;
        float4 w = *(const float4*)(p + 4);
        bf16x8 r;
        r[0] = f2b(u.x); r[1] = f2b(u.y); r[2] = f2b(u.z); r[3] = f2b(u.w);
        r[4] = f2b(w.x); r[5] = f2b(w.y); r[6] = f2b(w.z); r[7] = f2b(w.w);
        a0[kc] = r;
      }
      if (two) {
        #pragma unroll
        for (int kc = 0; kc < 4; ++kc) {
          const float* p = feat + (size_t)(m0 + 16 + lr) * DIM + kc * 32 + lk * 8;
          float4 u = *(const float4*)p;
          float4 w = *(const float4*)(p + 4);
          bf16x8 r;
          r[0] = f2b(u.x); r[1] = f2b(u.y); r[2] = f2b(u.z); r[3] = f2b(u.w);
          r[4] = f2b(w.x); r[5] = f2b(w.y); r[6] = f2b(w.z); r[7] = f2b(w.w);
          a1[kc] = r;
        }
      }
      #pragma unroll
      for (int nf = 0; nf < 24; ++nf) {      // all 384 output cols, one B read
        f32x4 acc0 = (f32x4){0.f, 0.f, 0.f, 0.f};
        f32x4 acc1 = (f32x4){0.f, 0.f, 0.f, 0.f};
        const int n = nf * 16 + lr;
        #pragma unroll
        for (int kc = 0; kc < 4; ++kc) {
          bf16x8 bw = *(const bf16x8*)(smem +
              ((n * 256 + kc * 64 + lk * 16) ^ ((n & 7) << 4)));
          acc0 = __builtin_amdgcn_mfma_f32_16x16x32_bf16(a0[kc], bw, acc0, 0, 0, 0);
          if (two)
            acc1 = __builtin_amdgcn_mfma_f32_16x16x32_bf16(a1[kc], bw, acc1, 0, 0, 0);
        }
        const int sec = nf >> 3;
        const int c0 = (nf & 7) * 16 + lr;   // col within section
        if (sec == 0) {                      // C/D: col=lane&15, row=(lane>>4)*4+j
          #pragma unroll
          for (int j = 0; j < 4; ++j) {
            g1b[(m0 + lk * 4 + j) * DIM + c0] = f2b(acc0[j] + bv[nf & 7]);
            if (two)
              g1b[(m0 + 16 + lk * 4 + j) * DIM + c0] = f2b(acc1[j] + bv[nf & 7]);
          }
        } else {
          unsigned char* gp = (sec == 1) ? g2f8 : g3f8;
          #pragma unroll
          for (int j = 0; j < 4; ++j) {
            unsigned int p8 = __builtin_amdgcn_cvt_pk_fp8_f32(acc0[j], acc0[j], 0, 0);
            gp[(m0 + lk * 4 + j) * DIM + c0] = (unsigned char)p8;
            if (two) {
              unsigned int q8 = __builtin_amdgcn_cvt_pk_fp8_f32(acc1[j], acc1[j], 0, 0);
              gp[(m0 + 16 + lk * 4 + j) * DIM + c0] = (unsigned char)q8;
            }
          }
        }
      }
    }
    return;
  }

  // ---- bin part (38KB of the union) ----
  int* fc = (int*)smem;
  int* bc = fc + 256;
  int* fo = bc + 256;
  int* bo = fo + 256;
  int* sa = bo + 256;
  int* sb2 = sa + 256;
  unsigned int* linf = (unsigned int*)(sb2 + 256);   // [CHUNK]
  unsigned int* linb = linf + CHUNK;                 // [CHUNK]

  const int bid = blockIdx.x - G;
  const int base = bid * CHUNK;
  const int n = min(CHUNK, E - base);
  if (t < 256) { fc[t] = 0; bc[t] = 0; }
  __syncthreads();
  int fbk[8], fsl[8], bsl[8], bbk[8];
  unsigned int fvv[8], bvv[8];
  #pragma unroll
  for (int j = 0; j < 8; ++j) {
    int e = base + j * 512 + t;
    fbk[j] = -1;
    if (e < E) {
      int s = src[e], d = dst[e];
      fbk[j] = d >> 8; fvv[j] = ((unsigned int)(d & 255) << 16) | (unsigned int)s;
      bbk[j] = s >> 8; bvv[j] = ((unsigned int)(s & 255) << 16) | (unsigned int)d;
      fsl[j] = atomicAdd(&fc[fbk[j]], 1);
      bsl[j] = atomicAdd(&bc[bbk[j]], 1);
    }
  }
  __syncthreads();
  if (t < 256) { sa[t] = fc[t]; sb2[t] = bc[t]; }
  __syncthreads();
  for (int s = 1; s < 256; s <<= 1) {   // Hillis-Steele inclusive scan
    int va = 0, vb = 0;
    if (t < 256) {
      va = sa[t] + ((t >= s) ? sa[t - s] : 0);
      vb = sb2[t] + ((t >= s) ? sb2[t - s] : 0);
    }
    __syncthreads();
    if (t < 256) { sa[t] = va; sb2[t] = vb; }
    __syncthreads();
  }
  if (t < 256) { fo[t] = sa[t] - fc[t]; bo[t] = sb2[t] - bc[t]; }
  __syncthreads();
  #pragma unroll
  for (int j = 0; j < 8; ++j) {
    if (fbk[j] >= 0) {
      linf[fo[fbk[j]] + fsl[j]] = fvv[j];
      linb[bo[bbk[j]] + bsl[j]] = bvv[j];
    }
  }
  if (t < 256) {
    offsF[bid * 256 + t] = fo[t];
    offsB[bid * 256 + t] = bo[t];
  }
  __syncthreads();
  for (int k = t; k < n; k += 512) {    // coalesced flush of reordered chunk
    scrF[base + k] = linf[k];
    scrB[base + k] = linb[k];
  }
}

// Launch 2: one block per (coarse bucket, dir), 33KB LDS (4+ blocks/CU):
// bin bucket edges into 256 per-node LDS lists, flush [node][64] + degrees.
__global__ __launch_bounds__(512) void k_csr(const unsigned int* __restrict__ scrF,
                                             const unsigned int* __restrict__ scrB,
                                             const int* __restrict__ offsF,
                                             const int* __restrict__ offsB,
                                             unsigned short* __restrict__ fnbr,
                                             unsigned short* __restrict__ bnbr,
                                             int* __restrict__ degF, int* __restrict__ degB,
                                             int N, int E, int nblk) {
  __shared__ int ncnt[256];
  __shared__ unsigned short nbuf[256][CAP];
  const int b = blockIdx.x;
  const int dir = blockIdx.y;
  const unsigned int* scr = dir ? scrB : scrF;
  const int* offs = dir ? offsB : offsF;
  const int t = threadIdx.x;
  if (t < 256) ncnt[t] = 0;
  __syncthreads();
  for (int i = t; i < nblk; i += 512) {
    int o = offs[i * 256 + b];
    int n = min(CHUNK, E - i * CHUNK);
    int nxt = (b < 255) ? offs[i * 256 + b + 1] : n;
    int cb = i * CHUNK;
    for (int k = o; k < nxt; ++k) {
      unsigned int v = scr[cb + k];
      int node8 = v >> 16;
      int slot = atomicAdd(&ncnt[node8], 1);
      if (slot < CAP) nbuf[node8][slot] = (unsigned short)(v & 0xFFFFu);
    }
  }
  __syncthreads();
  const int node0 = b * 256;
  const int nvalid = min(256, N - node0);
  if (nvalid <= 0) return;
  unsigned short* outp = (dir ? bnbr : fnbr) + (size_t)node0 * CAP;
  for (int idx = t; idx < nvalid * CAP; idx += 512)
    outp[idx] = nbuf[idx >> 6][idx & 63];
  int* deg = dir ? degB : degF;
  for (int u = t; u < nvalid; u += 512) deg[node0 + u] = ncnt[u];
}

// One wave per node (12500 blocks, proven TLP). NEW: 8-row-per-instruction
// gathers — lane = (qg=lane>>3: neighbor mod 8, sub=lane&7: 16B chunk), one
// uint4 load instruction covers EIGHT neighbor rows (1KB). Gather instrs per
// wave drop 8 -> 4 (all in flight at once). Reduce: shfl_xor(8,16,32).
// Epilogue: lanes 0-7 each own 16 output cols (64B).
__global__ void k_aggregate(const unsigned char* __restrict__ g2f8,
                            const unsigned char* __restrict__ g3f8,
                            const unsigned short* __restrict__ g1b,
                            const int* __restrict__ degF, const int* __restrict__ degB,
                            const unsigned short* __restrict__ fnbr,
                            const unsigned short* __restrict__ bnbr,
                            float* __restrict__ out, int N) {
  int node = blockIdx.x * (blockDim.x >> 6) + (threadIdx.x >> 6);
  if (node >= N) return;
  const int lane = threadIdx.x & 63;
  const int qg = lane >> 3;     // which neighbor (mod 8) this group gathers
  const int sub = lane & 7;     // 16B chunk within the 128B fp8 row

  const int degf = degF[node], degb = degB[node];
  const int capf = min(degf, CAP), capb = min(degb, CAP);
  const int fid = fnbr[node * CAP + lane];   // coalesced 128B list loads
  const int bid = bnbr[node * CAP + lane];

  const uint4* gf = (const uint4*)g2f8;      // row = 8 x uint4
  const uint4* gb = (const uint4*)g3f8;
  f32x2 fa[8], ba[8];
  #pragma unroll
  for (int i = 0; i < 8; ++i) { fa[i] = (f32x2){0.f, 0.f}; ba[i] = (f32x2){0.f, 0.f}; }
  const int gmax = (max(capf, capb) + 7) >> 3;   // <= 8
  #pragma unroll 4
  for (int g = 0; g < gmax; ++g) {
    int k = 8 * g + qg;
    int rf = __shfl(fid, k);
    int rb = __shfl(bid, k);
    if (k < capf) {
      uint4 v = gf[rf * 8 + sub];
      fa[0] += __builtin_amdgcn_cvt_pk_f32_fp8(v.x, 0);
      fa[1] += __builtin_amdgcn_cvt_pk_f32_fp8(v.x, 1);
      fa[2] += __builtin_amdgcn_cvt_pk_f32_fp8(v.y, 0);
      fa[3] += __builtin_amdgcn_cvt_pk_f32_fp8(v.y, 1);
      fa[4] += __builtin_amdgcn_cvt_pk_f32_fp8(v.z, 0);
      fa[5] += __builtin_amdgcn_cvt_pk_f32_fp8(v.z, 1);
      fa[6] += __builtin_amdgcn_cvt_pk_f32_fp8(v.w, 0);
      fa[7] += __builtin_amdgcn_cvt_pk_f32_fp8(v.w, 1);
    }
    if (k < capb) {
      uint4 v = gb[rb * 8 + sub];
      ba[0] += __builtin_amdgcn_cvt_pk_f32_fp8(v.x, 0);
      ba[1] += __builtin_amdgcn_cvt_pk_f32_fp8(v.x, 1);
      ba[2] += __builtin_amdgcn_cvt_pk_f32_fp8(v.y, 0);
      ba[3] += __builtin_amdgcn_cvt_pk_f32_fp8(v.y, 1);
      ba[4] += __builtin_amdgcn_cvt_pk_f32_fp8(v.z, 0);
      ba[5] += __builtin_amdgcn_cvt_pk_f32_fp8(v.z, 1);
      ba[6] += __builtin_amdgcn_cvt_pk_f32_fp8(v.w, 0);
      ba[7] += __builtin_amdgcn_cvt_pk_f32_fp8(v.w, 1);
    }
  }
  // flatten and reduce across the eight 8-lane groups
  float s[32];
  #pragma unroll
  for (int i = 0; i < 8; ++i) {
    s[2 * i] = fa[i][0]; s[2 * i + 1] = fa[i][1];
    s[16 + 2 * i] = ba[i][0]; s[16 + 2 * i + 1] = ba[i][1];
  }
  #pragma unroll
  for (int i = 0; i < 32; ++i) {
    s[i] += __shfl_xor(s[i], 8);
    s[i] += __shfl_xor(s[i], 16);
    s[i] += __shfl_xor(s[i], 32);
  }

  if (lane < 8) {  // lane owns output cols lane*16 .. lane*16+15 (64B)
    const float sf = (degf > 0) ? 1.0f / (float)degf : 0.0f;
    const float sb = (degb > 0) ? 1.0f / (float)degb : 0.0f;
    uint4 g1a = ((const uint4*)g1b)[node * 16 + lane * 2];       // 8 bf16
    uint4 g1c = ((const uint4*)g1b)[node * 16 + lane * 2 + 1];   // 8 bf16
    float o[16];
    o[0] = blo(g1a.x); o[1] = bhi(g1a.x); o[2] = blo(g1a.y); o[3] = bhi(g1a.y);
    o[4] = blo(g1a.z); o[5] = bhi(g1a.z); o[6] = blo(g1a.w); o[7] = bhi(g1a.w);
    o[8] = blo(g1c.x); o[9] = bhi(g1c.x); o[10] = blo(g1c.y); o[11] = bhi(g1c.y);
    o[12] = blo(g1c.z); o[13] = bhi(g1c.z); o[14] = blo(g1c.w); o[15] = bhi(g1c.w);
    #pragma unroll
    for (int i = 0; i < 16; ++i) o[i] += s[i] * sf + s[16 + i] * sb;
    float* op = out + node * DIM + lane * 16;
    #pragma unroll
    for (int q = 0; q < 4; ++q) {
      float4 w; w.x = o[4 * q]; w.y = o[4 * q + 1]; w.z = o[4 * q + 2]; w.w = o[4 * q + 3];
      *(float4*)(op + 4 * q) = w;
    }
  }
}

extern "C" void kernel_launch(void* const* d_in, const int* in_sizes, int n_in,
                              void* d_out, int out_size, void* d_ws, size_t ws_size,
                              hipStream_t stream) {
  (void)n_in; (void)out_size; (void)ws_size;
  const float* feat = (const float*)d_in[0];
  const int*   src  = (const int*)d_in[1];
  const int*   dst  = (const int*)d_in[2];
  const float* W    = (const float*)d_in[3];
  const float* bias = (const float*)d_in[4];
  float* out = (float*)d_out;
  const int N = in_sizes[0] / DIM;
  const int E = in_sizes[1];
  const int nblk = (E + CHUNK - 1) / CHUNK;        // 196
  const int nbkt = (N + 255) / 256;                // 196
  const int G = 192;                               // gemm blocks in launch 1

  char* ws = (char*)d_ws;
  size_t off = 0;
  auto take = [&](size_t bytes) -> void* {
    off = (off + 255) & ~(size_t)255;
    void* p = ws + off;
    off += bytes;
    return p;
  };
  unsigned int* scrF = (unsigned int*)take((size_t)nblk * CHUNK * 4);   // 3.2 MB
  unsigned int* scrB = (unsigned int*)take((size_t)nblk * CHUNK * 4);
  int* offsF = (int*)take((size_t)nblk * 256 * 4);                      // 0.2 MB
  int* offsB = (int*)take((size_t)nblk * 256 * 4);
  unsigned short* fnbr = (unsigned short*)take((size_t)N * CAP * 2);    // 6.4 MB
  unsigned short* bnbr = (unsigned short*)take((size_t)N * CAP * 2);
  int* degF = (int*)take((size_t)N * 4);
  int* degB = (int*)take((size_t)N * 4);
  unsigned short* g1b  = (unsigned short*)take((size_t)N * DIM * 2);    // 12.8 MB
  unsigned char*  g2f8 = (unsigned char*)take((size_t)N * DIM);         // 6.4 MB
  unsigned char*  g3f8 = (unsigned char*)take((size_t)N * DIM);         // 6.4 MB

  k_gemmbin<<<G + nblk, 512, 0, stream>>>(
      feat, W, bias, src, dst, g1b, g2f8, g3f8,
      scrF, scrB, offsF, offsB, N, E, G, nblk);
  k_csr<<<dim3(nbkt, 2), 512, 0, stream>>>(scrF, scrB, offsF, offsB,
                                           fnbr, bnbr, degF, degB, N, E, nblk);
  k_aggregate<<<(N + 3) / 4, 256, 0, stream>>>(g2f8, g3f8, g1b, degF, degB,
                                               fnbr, bnbr, out, N);
}

// Round 16
// 101.520 us; speedup vs baseline: 1.1368x; 1.1368x over previous
//
#include <hip/hip_runtime.h>

#define DIM 128     // D_IN == D_OUT == 128
#define CAP 64      // per-node neighbor capacity (Poisson(16); P(deg>64) ~ 1e-18/node)
#define CHUNK 4096  // edges per bin block (512 threads, 8 edges/thread)

typedef __attribute__((ext_vector_type(8))) short bf16x8;
typedef __attribute__((ext_vector_type(4))) float f32x4;
typedef __attribute__((ext_vector_type(2))) float f32x2;

__device__ __forceinline__ unsigned short f2b(float f) {  // f32 -> bf16 RNE (data has no NaN/Inf)
  unsigned int u = __float_as_uint(f);
  return (unsigned short)((u + 0x7FFFu + ((u >> 16) & 1u)) >> 16);
}
__device__ __forceinline__ float blo(unsigned int v) { return __uint_as_float(v << 16); }
__device__ __forceinline__ float bhi(unsigned int v) { return __uint_as_float(v & 0xFFFF0000u); }

// Launch 1:
//  blocks [0, G): one-pass GEMM. W (f32 [128][384]) staged ONCE per block into
//    LDS bf16 [n=384][k=128], XOR-swizzled -> ds_read_b128 ~2-way (free).
//    Each wave sweeps 64-row MACRO-tiles: one B-column sweep feeds FOUR 16-row
//    MFMA sub-tiles (ds:MFMA = 1:4; total GEMM ds_reads halved vs 32-row).
//    g1 = feat@W1^T+bias (bf16), g2 = feat@W2^T (fp8 e4m3), g3 = feat@W3^T (fp8).
//  blocks [G, G+nblk): LDS counting-sort binning of a 4096-edge chunk by
//    node>>8, both dirs. Coalesced writes only; no global atomics.
__global__ __launch_bounds__(512) void k_gemmbin(
    const float* __restrict__ feat, const float* __restrict__ W,
    const float* __restrict__ bias,
    const int* __restrict__ src, const int* __restrict__ dst,
    unsigned short* __restrict__ g1b, unsigned char* __restrict__ g2f8,
    unsigned char* __restrict__ g3f8,
    unsigned int* __restrict__ scrF, unsigned int* __restrict__ scrB,
    int* __restrict__ offsF, int* __restrict__ offsB,
    int N, int E, int G, int nblk) {
  __shared__ __align__(16) unsigned char smem[98304];   // 96KB union
  const int t = threadIdx.x;

  if ((int)blockIdx.x < G) {                 // ---- GEMM part ----
    for (int i = t; i < 12288; i += 512) {   // stage W -> LDS bf16, swizzled
      int flat = i * 4;
      int o = flat / 384;                    // W row = output col within section
      int kk = flat - o * 384;
      int n = (kk >> 7) * 128 + o;           // virtual concat col
      int k0 = kk & 127;
      float4 v = *(const float4*)(W + flat);
      ushort4 u; u.x = f2b(v.x); u.y = f2b(v.y); u.z = f2b(v.z); u.w = f2b(v.w);
      *(ushort4*)(smem + ((n * 256 + k0 * 2) ^ ((n & 7) << 4))) = u;
    }
    __syncthreads();

    const int wave = t >> 6, lane = t & 63;
    const int lr = lane & 15, lk = lane >> 4;
    float bv[8];
    #pragma unroll
    for (int i = 0; i < 8; ++i) bv[i] = bias[i * 16 + lr];

    const int MT = (N + 63) >> 6;            // 782 macro-tiles of 64 rows
    const int TW = G * 8;
    for (int mt = blockIdx.x * 8 + wave; mt < MT; mt += TW) {
      const int m0 = mt * 64;
      bf16x8 a[4][4];                        // [sub-tile][kc] — 64 VGPRs
      #pragma unroll
      for (int st = 0; st < 4; ++st) {
        const int row = min(m0 + st * 16 + lr, N - 1);   // clamp (N%16==0)
        #pragma unroll
        for (int kc = 0; kc < 4; ++kc) {     // feat f32 -> bf16 fragment
          const float* p = feat + (size_t)row * DIM + kc * 32 + lk * 8;
          float4 u = *(const float4*)p;
          float4 w = *(const float4*)(p + 4);
          bf16x8 r;
          r[0] = f2b(u.x); r[1] = f2b(u.y); r[2] = f2b(u.z); r[3] = f2b(u.w);
          r[4] = f2b(w.x); r[5] = f2b(w.y); r[6] = f2b(w.z); r[7] = f2b(w.w);
          a[st][kc] = r;
        }
      }
      #pragma unroll
      for (int nf = 0; nf < 24; ++nf) {      // all 384 cols; 4 ds_read -> 16 MFMA
        f32x4 acc[4];
        #pragma unroll
        for (int st = 0; st < 4; ++st) acc[st] = (f32x4){0.f, 0.f, 0.f, 0.f};
        const int n = nf * 16 + lr;
        #pragma unroll
        for (int kc = 0; kc < 4; ++kc) {
          bf16x8 bw = *(const bf16x8*)(smem +
              ((n * 256 + kc * 64 + lk * 16) ^ ((n & 7) << 4)));
          #pragma unroll
          for (int st = 0; st < 4; ++st)
            acc[st] = __builtin_amdgcn_mfma_f32_16x16x32_bf16(a[st][kc], bw, acc[st], 0, 0, 0);
        }
        const int sec = nf >> 3;
        const int c0 = (nf & 7) * 16 + lr;   // col within section
        if (sec == 0) {                      // C/D: col=lane&15, row=(lane>>4)*4+j
          #pragma unroll
          for (int st = 0; st < 4; ++st) {
            if (m0 + st * 16 < N) {
              #pragma unroll
              for (int j = 0; j < 4; ++j)
                g1b[(m0 + st * 16 + lk * 4 + j) * DIM + c0] = f2b(acc[st][j] + bv[nf & 7]);
            }
          }
        } else {
          unsigned char* gp = (sec == 1) ? g2f8 : g3f8;
          #pragma unroll
          for (int st = 0; st < 4; ++st) {
            if (m0 + st * 16 < N) {
              #pragma unroll
              for (int j = 0; j < 4; ++j) {
                unsigned int p8 = __builtin_amdgcn_cvt_pk_fp8_f32(acc[st][j], acc[st][j], 0, 0);
                gp[(m0 + st * 16 + lk * 4 + j) * DIM + c0] = (unsigned char)p8;
              }
            }
          }
        }
      }
    }
    return;
  }

  // ---- bin part (38KB of the union) ----
  int* fc = (int*)smem;
  int* bc = fc + 256;
  int* fo = bc + 256;
  int* bo = fo + 256;
  int* sa = bo + 256;
  int* sb2 = sa + 256;
  unsigned int* linf = (unsigned int*)(sb2 + 256);   // [CHUNK]
  unsigned int* linb = linf + CHUNK;                 // [CHUNK]

  const int bid = blockIdx.x - G;
  const int base = bid * CHUNK;
  const int n = min(CHUNK, E - base);
  if (t < 256) { fc[t] = 0; bc[t] = 0; }
  __syncthreads();
  int fbk[8], fsl[8], bsl[8], bbk[8];
  unsigned int fvv[8], bvv[8];
  #pragma unroll
  for (int j = 0; j < 8; ++j) {
    int e = base + j * 512 + t;
    fbk[j] = -1;
    if (e < E) {
      int s = src[e], d = dst[e];
      fbk[j] = d >> 8; fvv[j] = ((unsigned int)(d & 255) << 16) | (unsigned int)s;
      bbk[j] = s >> 8; bvv[j] = ((unsigned int)(s & 255) << 16) | (unsigned int)d;
      fsl[j] = atomicAdd(&fc[fbk[j]], 1);
      bsl[j] = atomicAdd(&bc[bbk[j]], 1);
    }
  }
  __syncthreads();
  if (t < 256) { sa[t] = fc[t]; sb2[t] = bc[t]; }
  __syncthreads();
  for (int s = 1; s < 256; s <<= 1) {   // Hillis-Steele inclusive scan
    int va = 0, vb = 0;
    if (t < 256) {
      va = sa[t] + ((t >= s) ? sa[t - s] : 0);
      vb = sb2[t] + ((t >= s) ? sb2[t - s] : 0);
    }
    __syncthreads();
    if (t < 256) { sa[t] = va; sb2[t] = vb; }
    __syncthreads();
  }
  if (t < 256) { fo[t] = sa[t] - fc[t]; bo[t] = sb2[t] - bc[t]; }
  __syncthreads();
  #pragma unroll
  for (int j = 0; j < 8; ++j) {
    if (fbk[j] >= 0) {
      linf[fo[fbk[j]] + fsl[j]] = fvv[j];
      linb[bo[bbk[j]] + bsl[j]] = bvv[j];
    }
  }
  if (t < 256) {
    offsF[bid * 256 + t] = fo[t];
    offsB[bid * 256 + t] = bo[t];
  }
  __syncthreads();
  for (int k = t; k < n; k += 512) {    // coalesced flush of reordered chunk
    scrF[base + k] = linf[k];
    scrB[base + k] = linb[k];
  }
}

// Launch 2: one block per (coarse bucket, dir), 33KB LDS:
// bin bucket edges into 256 per-node LDS lists, flush [node][64] + degrees.
__global__ __launch_bounds__(512) void k_csr(const unsigned int* __restrict__ scrF,
                                             const unsigned int* __restrict__ scrB,
                                             const int* __restrict__ offsF,
                                             const int* __restrict__ offsB,
                                             unsigned short* __restrict__ fnbr,
                                             unsigned short* __restrict__ bnbr,
                                             int* __restrict__ degF, int* __restrict__ degB,
                                             int N, int E, int nblk) {
  __shared__ int ncnt[256];
  __shared__ unsigned short nbuf[256][CAP];
  const int b = blockIdx.x;
  const int dir = blockIdx.y;
  const unsigned int* scr = dir ? scrB : scrF;
  const int* offs = dir ? offsB : offsF;
  const int t = threadIdx.x;
  if (t < 256) ncnt[t] = 0;
  __syncthreads();
  for (int i = t; i < nblk; i += 512) {
    int o = offs[i * 256 + b];
    int n = min(CHUNK, E - i * CHUNK);
    int nxt = (b < 255) ? offs[i * 256 + b + 1] : n;
    int cb = i * CHUNK;
    for (int k = o; k < nxt; ++k) {
      unsigned int v = scr[cb + k];
      int node8 = v >> 16;
      int slot = atomicAdd(&ncnt[node8], 1);
      if (slot < CAP) nbuf[node8][slot] = (unsigned short)(v & 0xFFFFu);
    }
  }
  __syncthreads();
  const int node0 = b * 256;
  const int nvalid = min(256, N - node0);
  if (nvalid <= 0) return;
  unsigned short* outp = (dir ? bnbr : fnbr) + (size_t)node0 * CAP;
  for (int idx = t; idx < nvalid * CAP; idx += 512)
    outp[idx] = nbuf[idx >> 6][idx & 63];
  int* deg = dir ? degB : degF;
  for (int u = t; u < nvalid; u += 512) deg[node0 + u] = ncnt[u];
}

// One wave per node (12500 blocks) — PROVEN 46.5us structure, restored
// verbatim (4-row/16-lane gathers, uint2, 2-level shfl_xor reduce, 32-bit idx).
__global__ void k_aggregate(const unsigned char* __restrict__ g2f8,
                            const unsigned char* __restrict__ g3f8,
                            const unsigned short* __restrict__ g1b,
                            const int* __restrict__ degF, const int* __restrict__ degB,
                            const unsigned short* __restrict__ fnbr,
                            const unsigned short* __restrict__ bnbr,
                            float* __restrict__ out, int N) {
  int node = blockIdx.x * (blockDim.x >> 6) + (threadIdx.x >> 6);
  if (node >= N) return;
  const int lane = threadIdx.x & 63;
  const int qg = lane >> 4;     // neighbor sub-index (mod 4) this group gathers
  const int sub = lane & 15;    // 8B chunk within the 128B fp8 row

  const int degf = degF[node], degb = degB[node];
  const int capf = min(degf, CAP), capb = min(degb, CAP);
  const int fid = fnbr[node * CAP + lane];
  const int bid = bnbr[node * CAP + lane];

  const uint2* gf = (const uint2*)g2f8;   // row = 16 x uint2
  const uint2* gb = (const uint2*)g3f8;
  f32x2 f01 = {0.f, 0.f}, f23 = {0.f, 0.f}, f45 = {0.f, 0.f}, f67 = {0.f, 0.f};
  f32x2 b01 = {0.f, 0.f}, b23 = {0.f, 0.f}, b45 = {0.f, 0.f}, b67 = {0.f, 0.f};
  const int gmax = (max(capf, capb) + 3) >> 2;
  #pragma unroll 4
  for (int g = 0; g < gmax; ++g) {
    int k = 4 * g + qg;
    int rf = __shfl(fid, k);
    int rb = __shfl(bid, k);
    if (k < capf) {
      uint2 v = gf[rf * 16 + sub];
      f01 += __builtin_amdgcn_cvt_pk_f32_fp8(v.x, 0);
      f23 += __builtin_amdgcn_cvt_pk_f32_fp8(v.x, 1);
      f45 += __builtin_amdgcn_cvt_pk_f32_fp8(v.y, 0);
      f67 += __builtin_amdgcn_cvt_pk_f32_fp8(v.y, 1);
    }
    if (k < capb) {
      uint2 v = gb[rb * 16 + sub];
      b01 += __builtin_amdgcn_cvt_pk_f32_fp8(v.x, 0);
      b23 += __builtin_amdgcn_cvt_pk_f32_fp8(v.x, 1);
      b45 += __builtin_amdgcn_cvt_pk_f32_fp8(v.y, 0);
      b67 += __builtin_amdgcn_cvt_pk_f32_fp8(v.y, 1);
    }
  }
  float fa0 = f01[0], fa1 = f01[1], fa2 = f23[0], fa3 = f23[1];
  float fa4 = f45[0], fa5 = f45[1], fa6 = f67[0], fa7 = f67[1];
  float ba0 = b01[0], ba1 = b01[1], ba2 = b23[0], ba3 = b23[1];
  float ba4 = b45[0], ba5 = b45[1], ba6 = b67[0], ba7 = b67[1];
  fa0 += __shfl_xor(fa0, 16); fa0 += __shfl_xor(fa0, 32);
  fa1 += __shfl_xor(fa1, 16); fa1 += __shfl_xor(fa1, 32);
  fa2 += __shfl_xor(fa2, 16); fa2 += __shfl_xor(fa2, 32);
  fa3 += __shfl_xor(fa3, 16); fa3 += __shfl_xor(fa3, 32);
  fa4 += __shfl_xor(fa4, 16); fa4 += __shfl_xor(fa4, 32);
  fa5 += __shfl_xor(fa5, 16); fa5 += __shfl_xor(fa5, 32);
  fa6 += __shfl_xor(fa6, 16); fa6 += __shfl_xor(fa6, 32);
  fa7 += __shfl_xor(fa7, 16); fa7 += __shfl_xor(fa7, 32);
  ba0 += __shfl_xor(ba0, 16); ba0 += __shfl_xor(ba0, 32);
  ba1 += __shfl_xor(ba1, 16); ba1 += __shfl_xor(ba1, 32);
  ba2 += __shfl_xor(ba2, 16); ba2 += __shfl_xor(ba2, 32);
  ba3 += __shfl_xor(ba3, 16); ba3 += __shfl_xor(ba3, 32);
  ba4 += __shfl_xor(ba4, 16); ba4 += __shfl_xor(ba4, 32);
  ba5 += __shfl_xor(ba5, 16); ba5 += __shfl_xor(ba5, 32);
  ba6 += __shfl_xor(ba6, 16); ba6 += __shfl_xor(ba6, 32);
  ba7 += __shfl_xor(ba7, 16); ba7 += __shfl_xor(ba7, 32);

  if (lane < 16) {  // lane owns cols lane*8..lane*8+7 of the output row
    const float sf = (degf > 0) ? 1.0f / (float)degf : 0.0f;
    const float sb = (degb > 0) ? 1.0f / (float)degb : 0.0f;
    uint4 g1v = ((const uint4*)g1b)[node * 16 + lane];
    float4 u, v;
    u.x = blo(g1v.x) + fa0 * sf + ba0 * sb;
    u.y = bhi(g1v.x) + fa1 * sf + ba1 * sb;
    u.z = blo(g1v.y) + fa2 * sf + ba2 * sb;
    u.w = bhi(g1v.y) + fa3 * sf + ba3 * sb;
    v.x = blo(g1v.z) + fa4 * sf + ba4 * sb;
    v.y = bhi(g1v.z) + fa5 * sf + ba5 * sb;
    v.z = blo(g1v.w) + fa6 * sf + ba6 * sb;
    v.w = bhi(g1v.w) + fa7 * sf + ba7 * sb;
    float* op = out + node * DIM + lane * 8;
    *(float4*)op = u; *(float4*)(op + 4) = v;
  }
}

extern "C" void kernel_launch(void* const* d_in, const int* in_sizes, int n_in,
                              void* d_out, int out_size, void* d_ws, size_t ws_size,
                              hipStream_t stream) {
  (void)n_in; (void)out_size; (void)ws_size;
  const float* feat = (const float*)d_in[0];
  const int*   src  = (const int*)d_in[1];
  const int*   dst  = (const int*)d_in[2];
  const float* W    = (const float*)d_in[3];
  const float* bias = (const float*)d_in[4];
  float* out = (float*)d_out;
  const int N = in_sizes[0] / DIM;
  const int E = in_sizes[1];
  const int nblk = (E + CHUNK - 1) / CHUNK;        // 196
  const int nbkt = (N + 255) / 256;                // 196
  const int G = 192;                               // gemm blocks in launch 1

  char* ws = (char*)d_ws;
  size_t off = 0;
  auto take = [&](size_t bytes) -> void* {
    off = (off + 255) & ~(size_t)255;
    void* p = ws + off;
    off += bytes;
    return p;
  };
  unsigned int* scrF = (unsigned int*)take((size_t)nblk * CHUNK * 4);   // 3.2 MB
  unsigned int* scrB = (unsigned int*)take((size_t)nblk * CHUNK * 4);
  int* offsF = (int*)take((size_t)nblk * 256 * 4);                      // 0.2 MB
  int* offsB = (int*)take((size_t)nblk * 256 * 4);
  unsigned short* fnbr = (unsigned short*)take((size_t)N * CAP * 2);    // 6.4 MB
  unsigned short* bnbr = (unsigned short*)take((size_t)N * CAP * 2);
  int* degF = (int*)take((size_t)N * 4);
  int* degB = (int*)take((size_t)N * 4);
  unsigned short* g1b  = (unsigned short*)take((size_t)N * DIM * 2);    // 12.8 MB
  unsigned char*  g2f8 = (unsigned char*)take((size_t)N * DIM);         // 6.4 MB
  unsigned char*  g3f8 = (unsigned char*)take((size_t)N * DIM);         // 6.4 MB

  k_gemmbin<<<G + nblk, 512, 0, stream>>>(
      feat, W, bias, src, dst, g1b, g2f8, g3f8,
      scrF, scrB, offsF, offsB, N, E, G, nblk);
  k_csr<<<dim3(nbkt, 2), 512, 0, stream>>>(scrF, scrB, offsF, offsB,
                                           fnbr, bnbr, degF, degB, N, E, nblk);
  k_aggregate<<<(N + 3) / 4, 256, 0, stream>>>(g2f8, g3f8, g1b, degF, degB,
                                               fnbr, bnbr, out, N);
}

// Round 17
// 96.218 us; speedup vs baseline: 1.1995x; 1.0551x over previous
//
#include <hip/hip_runtime.h>

#define DIM 128     // D_IN == D_OUT == 128
#define CAP 64      // per-node neighbor capacity (Poisson(16); P(deg>64) ~ 1e-18/node)
#define CHUNK 4096  // edges per bin block (512 threads, 8 edges/thread)

typedef __attribute__((ext_vector_type(8))) short bf16x8;
typedef __attribute__((ext_vector_type(4))) float f32x4;
typedef __attribute__((ext_vector_type(2))) float f32x2;

__device__ __forceinline__ unsigned short f2b(float f) {  // f32 -> bf16 RNE (data has no NaN/Inf)
  unsigned int u = __float_as_uint(f);
  return (unsigned short)((u + 0x7FFFu + ((u >> 16) & 1u)) >> 16);
}
__device__ __forceinline__ float blo(unsigned int v) { return __uint_as_float(v << 16); }
__device__ __forceinline__ float bhi(unsigned int v) { return __uint_as_float(v & 0xFFFF0000u); }

// Launch 1 (best-measured config, 96.3us total, restored):
//  blocks [0, G): one-pass GEMM. W (f32 [128][384]) staged ONCE per block into
//    LDS bf16 [n=384][k=128], XOR-swizzled -> ds_read_b128 ~2-way (free).
//    Each wave sweeps 32-row macro-tiles (one B sweep feeds TWO 16-row tiles).
//    g1 = feat@W1^T+bias (bf16), g2 = feat@W2^T (fp8 e4m3), g3 = feat@W3^T (fp8).
//  blocks [G, G+nblk): LDS counting-sort binning of a 4096-edge chunk by
//    node>>8, both dirs. Coalesced writes only; no global atomics.
__global__ __launch_bounds__(512) void k_gemmbin(
    const float* __restrict__ feat, const float* __restrict__ W,
    const float* __restrict__ bias,
    const int* __restrict__ src, const int* __restrict__ dst,
    unsigned short* __restrict__ g1b, unsigned char* __restrict__ g2f8,
    unsigned char* __restrict__ g3f8,
    unsigned int* __restrict__ scrF, unsigned int* __restrict__ scrB,
    int* __restrict__ offsF, int* __restrict__ offsB,
    int N, int E, int G, int nblk) {
  __shared__ __align__(16) unsigned char smem[98304];   // 96KB union
  const int t = threadIdx.x;

  if ((int)blockIdx.x < G) {                 // ---- GEMM part ----
    for (int i = t; i < 12288; i += 512) {   // stage W -> LDS bf16, swizzled
      int flat = i * 4;
      int o = flat / 384;                    // W row = output col within section
      int kk = flat - o * 384;
      int n = (kk >> 7) * 128 + o;           // virtual concat col
      int k0 = kk & 127;
      float4 v = *(const float4*)(W + flat);
      ushort4 u; u.x = f2b(v.x); u.y = f2b(v.y); u.z = f2b(v.z); u.w = f2b(v.w);
      *(ushort4*)(smem + ((n * 256 + k0 * 2) ^ ((n & 7) << 4))) = u;
    }
    __syncthreads();

    const int wave = t >> 6, lane = t & 63;
    const int lr = lane & 15, lk = lane >> 4;
    float bv[8];
    #pragma unroll
    for (int i = 0; i < 8; ++i) bv[i] = bias[i * 16 + lr];

    const int MT = (N + 31) >> 5;            // 1563 macro-tiles of 32 rows
    const int TW = G * 8;                    // 1664 waves >= MT: <=1 tile/wave
    for (int mt = blockIdx.x * 8 + wave; mt < MT; mt += TW) {
      const int m0 = mt * 32;
      const bool two = (m0 + 16 < N);
      bf16x8 a0[4], a1[4];
      #pragma unroll
      for (int kc = 0; kc < 4; ++kc) {       // feat f32 -> bf16 fragments
        const float* p = feat + (size_t)(m0 + lr) * DIM + kc * 32 + lk * 8;
        float4 u = *(const float4*)p;
        float4 w = *(const float4*)(p + 4);
        bf16x8 r;
        r[0] = f2b(u.x); r[1] = f2b(u.y); r[2] = f2b(u.z); r[3] = f2b(u.w);
        r[4] = f2b(w.x); r[5] = f2b(w.y); r[6] = f2b(w.z); r[7] = f2b(w.w);
        a0[kc] = r;
      }
      if (two) {
        #pragma unroll
        for (int kc = 0; kc < 4; ++kc) {
          const float* p = feat + (size_t)(m0 + 16 + lr) * DIM + kc * 32 + lk * 8;
          float4 u = *(const float4*)p;
          float4 w = *(const float4*)(p + 4);
          bf16x8 r;
          r[0] = f2b(u.x); r[1] = f2b(u.y); r[2] = f2b(u.z); r[3] = f2b(u.w);
          r[4] = f2b(w.x); r[5] = f2b(w.y); r[6] = f2b(w.z); r[7] = f2b(w.w);
          a1[kc] = r;
        }
      }
      #pragma unroll
      for (int nf = 0; nf < 24; ++nf) {      // all 384 output cols, one B read
        f32x4 acc0 = (f32x4){0.f, 0.f, 0.f, 0.f};
        f32x4 acc1 = (f32x4){0.f, 0.f, 0.f, 0.f};
        const int n = nf * 16 + lr;
        #pragma unroll
        for (int kc = 0; kc < 4; ++kc) {
          bf16x8 bw = *(const bf16x8*)(smem +
              ((n * 256 + kc * 64 + lk * 16) ^ ((n & 7) << 4)));
          acc0 = __builtin_amdgcn_mfma_f32_16x16x32_bf16(a0[kc], bw, acc0, 0, 0, 0);
          if (two)
            acc1 = __builtin_amdgcn_mfma_f32_16x16x32_bf16(a1[kc], bw, acc1, 0, 0, 0);
        }
        const int sec = nf >> 3;
        const int c0 = (nf & 7) * 16 + lr;   // col within section
        if (sec == 0) {                      // C/D: col=lane&15, row=(lane>>4)*4+j
          #pragma unroll
          for (int j = 0; j < 4; ++j) {
            g1b[(m0 + lk * 4 + j) * DIM + c0] = f2b(acc0[j] + bv[nf & 7]);
            if (two)
              g1b[(m0 + 16 + lk * 4 + j) * DIM + c0] = f2b(acc1[j] + bv[nf & 7]);
          }
        } else {
          unsigned char* gp = (sec == 1) ? g2f8 : g3f8;
          #pragma unroll
          for (int j = 0; j < 4; ++j) {
            unsigned int p8 = __builtin_amdgcn_cvt_pk_fp8_f32(acc0[j], acc0[j], 0, 0);
            gp[(m0 + lk * 4 + j) * DIM + c0] = (unsigned char)p8;
            if (two) {
              unsigned int q8 = __builtin_amdgcn_cvt_pk_fp8_f32(acc1[j], acc1[j], 0, 0);
              gp[(m0 + 16 + lk * 4 + j) * DIM + c0] = (unsigned char)q8;
            }
          }
        }
      }
    }
    return;
  }

  // ---- bin part (38KB of the union) ----
  int* fc = (int*)smem;
  int* bc = fc + 256;
  int* fo = bc + 256;
  int* bo = fo + 256;
  int* sa = bo + 256;
  int* sb2 = sa + 256;
  unsigned int* linf = (unsigned int*)(sb2 + 256);   // [CHUNK]
  unsigned int* linb = linf + CHUNK;                 // [CHUNK]

  const int bid = blockIdx.x - G;
  const int base = bid * CHUNK;
  const int n = min(CHUNK, E - base);
  if (t < 256) { fc[t] = 0; bc[t] = 0; }
  __syncthreads();
  int fbk[8], fsl[8], bsl[8], bbk[8];
  unsigned int fvv[8], bvv[8];
  #pragma unroll
  for (int j = 0; j < 8; ++j) {
    int e = base + j * 512 + t;
    fbk[j] = -1;
    if (e < E) {
      int s = src[e], d = dst[e];
      fbk[j] = d >> 8; fvv[j] = ((unsigned int)(d & 255) << 16) | (unsigned int)s;
      bbk[j] = s >> 8; bvv[j] = ((unsigned int)(s & 255) << 16) | (unsigned int)d;
      fsl[j] = atomicAdd(&fc[fbk[j]], 1);
      bsl[j] = atomicAdd(&bc[bbk[j]], 1);
    }
  }
  __syncthreads();
  if (t < 256) { sa[t] = fc[t]; sb2[t] = bc[t]; }
  __syncthreads();
  for (int s = 1; s < 256; s <<= 1) {   // Hillis-Steele inclusive scan
    int va = 0, vb = 0;
    if (t < 256) {
      va = sa[t] + ((t >= s) ? sa[t - s] : 0);
      vb = sb2[t] + ((t >= s) ? sb2[t - s] : 0);
    }
    __syncthreads();
    if (t < 256) { sa[t] = va; sb2[t] = vb; }
    __syncthreads();
  }
  if (t < 256) { fo[t] = sa[t] - fc[t]; bo[t] = sb2[t] - bc[t]; }
  __syncthreads();
  #pragma unroll
  for (int j = 0; j < 8; ++j) {
    if (fbk[j] >= 0) {
      linf[fo[fbk[j]] + fsl[j]] = fvv[j];
      linb[bo[bbk[j]] + bsl[j]] = bvv[j];
    }
  }
  if (t < 256) {
    offsF[bid * 256 + t] = fo[t];
    offsB[bid * 256 + t] = bo[t];
  }
  __syncthreads();
  for (int k = t; k < n; k += 512) {    // coalesced flush of reordered chunk
    scrF[base + k] = linf[k];
    scrB[base + k] = linb[k];
  }
}

// Launch 2: one block per (coarse bucket, dir), 33KB LDS:
// bin bucket edges into 256 per-node LDS lists, flush [node][64] + degrees.
__global__ __launch_bounds__(512) void k_csr(const unsigned int* __restrict__ scrF,
                                             const unsigned int* __restrict__ scrB,
                                             const int* __restrict__ offsF,
                                             const int* __restrict__ offsB,
                                             unsigned short* __restrict__ fnbr,
                                             unsigned short* __restrict__ bnbr,
                                             int* __restrict__ degF, int* __restrict__ degB,
                                             int N, int E, int nblk) {
  __shared__ int ncnt[256];
  __shared__ unsigned short nbuf[256][CAP];
  const int b = blockIdx.x;
  const int dir = blockIdx.y;
  const unsigned int* scr = dir ? scrB : scrF;
  const int* offs = dir ? offsB : offsF;
  const int t = threadIdx.x;
  if (t < 256) ncnt[t] = 0;
  __syncthreads();
  for (int i = t; i < nblk; i += 512) {
    int o = offs[i * 256 + b];
    int n = min(CHUNK, E - i * CHUNK);
    int nxt = (b < 255) ? offs[i * 256 + b + 1] : n;
    int cb = i * CHUNK;
    for (int k = o; k < nxt; ++k) {
      unsigned int v = scr[cb + k];
      int node8 = v >> 16;
      int slot = atomicAdd(&ncnt[node8], 1);
      if (slot < CAP) nbuf[node8][slot] = (unsigned short)(v & 0xFFFFu);
    }
  }
  __syncthreads();
  const int node0 = b * 256;
  const int nvalid = min(256, N - node0);
  if (nvalid <= 0) return;
  unsigned short* outp = (dir ? bnbr : fnbr) + (size_t)node0 * CAP;
  for (int idx = t; idx < nvalid * CAP; idx += 512)
    outp[idx] = nbuf[idx >> 6][idx & 63];
  int* deg = dir ? degB : degF;
  for (int u = t; u < nvalid; u += 512) deg[node0 + u] = ncnt[u];
}

// One wave per node (12500 blocks) — PROVEN 46.5us structure, verbatim
// (4-row/16-lane gathers, uint2, 2-level shfl_xor reduce, 32-bit idx).
__global__ void k_aggregate(const unsigned char* __restrict__ g2f8,
                            const unsigned char* __restrict__ g3f8,
                            const unsigned short* __restrict__ g1b,
                            const int* __restrict__ degF, const int* __restrict__ degB,
                            const unsigned short* __restrict__ fnbr,
                            const unsigned short* __restrict__ bnbr,
                            float* __restrict__ out, int N) {
  int node = blockIdx.x * (blockDim.x >> 6) + (threadIdx.x >> 6);
  if (node >= N) return;
  const int lane = threadIdx.x & 63;
  const int qg = lane >> 4;     // neighbor sub-index (mod 4) this group gathers
  const int sub = lane & 15;    // 8B chunk within the 128B fp8 row

  const int degf = degF[node], degb = degB[node];
  const int capf = min(degf, CAP), capb = min(degb, CAP);
  const int fid = fnbr[node * CAP + lane];
  const int bid = bnbr[node * CAP + lane];

  const uint2* gf = (const uint2*)g2f8;   // row = 16 x uint2
  const uint2* gb = (const uint2*)g3f8;
  f32x2 f01 = {0.f, 0.f}, f23 = {0.f, 0.f}, f45 = {0.f, 0.f}, f67 = {0.f, 0.f};
  f32x2 b01 = {0.f, 0.f}, b23 = {0.f, 0.f}, b45 = {0.f, 0.f}, b67 = {0.f, 0.f};
  const int gmax = (max(capf, capb) + 3) >> 2;
  #pragma unroll 4
  for (int g = 0; g < gmax; ++g) {
    int k = 4 * g + qg;
    int rf = __shfl(fid, k);
    int rb = __shfl(bid, k);
    if (k < capf) {
      uint2 v = gf[rf * 16 + sub];
      f01 += __builtin_amdgcn_cvt_pk_f32_fp8(v.x, 0);
      f23 += __builtin_amdgcn_cvt_pk_f32_fp8(v.x, 1);
      f45 += __builtin_amdgcn_cvt_pk_f32_fp8(v.y, 0);
      f67 += __builtin_amdgcn_cvt_pk_f32_fp8(v.y, 1);
    }
    if (k < capb) {
      uint2 v = gb[rb * 16 + sub];
      b01 += __builtin_amdgcn_cvt_pk_f32_fp8(v.x, 0);
      b23 += __builtin_amdgcn_cvt_pk_f32_fp8(v.x, 1);
      b45 += __builtin_amdgcn_cvt_pk_f32_fp8(v.y, 0);
      b67 += __builtin_amdgcn_cvt_pk_f32_fp8(v.y, 1);
    }
  }
  float fa0 = f01[0], fa1 = f01[1], fa2 = f23[0], fa3 = f23[1];
  float fa4 = f45[0], fa5 = f45[1], fa6 = f67[0], fa7 = f67[1];
  float ba0 = b01[0], ba1 = b01[1], ba2 = b23[0], ba3 = b23[1];
  float ba4 = b45[0], ba5 = b45[1], ba6 = b67[0], ba7 = b67[1];
  fa0 += __shfl_xor(fa0, 16); fa0 += __shfl_xor(fa0, 32);
  fa1 += __shfl_xor(fa1, 16); fa1 += __shfl_xor(fa1, 32);
  fa2 += __shfl_xor(fa2, 16); fa2 += __shfl_xor(fa2, 32);
  fa3 += __shfl_xor(fa3, 16); fa3 += __shfl_xor(fa3, 32);
  fa4 += __shfl_xor(fa4, 16); fa4 += __shfl_xor(fa4, 32);
  fa5 += __shfl_xor(fa5, 16); fa5 += __shfl_xor(fa5, 32);
  fa6 += __shfl_xor(fa6, 16); fa6 += __shfl_xor(fa6, 32);
  fa7 += __shfl_xor(fa7, 16); fa7 += __shfl_xor(fa7, 32);
  ba0 += __shfl_xor(ba0, 16); ba0 += __shfl_xor(ba0, 32);
  ba1 += __shfl_xor(ba1, 16); ba1 += __shfl_xor(ba1, 32);
  ba2 += __shfl_xor(ba2, 16); ba2 += __shfl_xor(ba2, 32);
  ba3 += __shfl_xor(ba3, 16); ba3 += __shfl_xor(ba3, 32);
  ba4 += __shfl_xor(ba4, 16); ba4 += __shfl_xor(ba4, 32);
  ba5 += __shfl_xor(ba5, 16); ba5 += __shfl_xor(ba5, 32);
  ba6 += __shfl_xor(ba6, 16); ba6 += __shfl_xor(ba6, 32);
  ba7 += __shfl_xor(ba7, 16); ba7 += __shfl_xor(ba7, 32);

  if (lane < 16) {  // lane owns cols lane*8..lane*8+7 of the output row
    const float sf = (degf > 0) ? 1.0f / (float)degf : 0.0f;
    const float sb = (degb > 0) ? 1.0f / (float)degb : 0.0f;
    uint4 g1v = ((const uint4*)g1b)[node * 16 + lane];
    float4 u, v;
    u.x = blo(g1v.x) + fa0 * sf + ba0 * sb;
    u.y = bhi(g1v.x) + fa1 * sf + ba1 * sb;
    u.z = blo(g1v.y) + fa2 * sf + ba2 * sb;
    u.w = bhi(g1v.y) + fa3 * sf + ba3 * sb;
    v.x = blo(g1v.z) + fa4 * sf + ba4 * sb;
    v.y = bhi(g1v.z) + fa5 * sf + ba5 * sb;
    v.z = blo(g1v.w) + fa6 * sf + ba6 * sb;
    v.w = bhi(g1v.w) + fa7 * sf + ba7 * sb;
    float* op = out + node * DIM + lane * 8;
    *(float4*)op = u; *(float4*)(op + 4) = v;
  }
}

extern "C" void kernel_launch(void* const* d_in, const int* in_sizes, int n_in,
                              void* d_out, int out_size, void* d_ws, size_t ws_size,
                              hipStream_t stream) {
  (void)n_in; (void)out_size; (void)ws_size;
  const float* feat = (const float*)d_in[0];
  const int*   src  = (const int*)d_in[1];
  const int*   dst  = (const int*)d_in[2];
  const float* W    = (const float*)d_in[3];
  const float* bias = (const float*)d_in[4];
  float* out = (float*)d_out;
  const int N = in_sizes[0] / DIM;
  const int E = in_sizes[1];
  const int nblk = (E + CHUNK - 1) / CHUNK;        // 196
  const int nbkt = (N + 255) / 256;                // 196
  const int G = 208;                               // 1664 gemm waves >= 1563 tiles

  char* ws = (char*)d_ws;
  size_t off = 0;
  auto take = [&](size_t bytes) -> void* {
    off = (off + 255) & ~(size_t)255;
    void* p = ws + off;
    off += bytes;
    return p;
  };
  unsigned int* scrF = (unsigned int*)take((size_t)nblk * CHUNK * 4);   // 3.2 MB
  unsigned int* scrB = (unsigned int*)take((size_t)nblk * CHUNK * 4);
  int* offsF = (int*)take((size_t)nblk * 256 * 4);                      // 0.2 MB
  int* offsB = (int*)take((size_t)nblk * 256 * 4);
  unsigned short* fnbr = (unsigned short*)take((size_t)N * CAP * 2);    // 6.4 MB
  unsigned short* bnbr = (unsigned short*)take((size_t)N * CAP * 2);
  int* degF = (int*)take((size_t)N * 4);
  int* degB = (int*)take((size_t)N * 4);
  unsigned short* g1b  = (unsigned short*)take((size_t)N * DIM * 2);    // 12.8 MB
  unsigned char*  g2f8 = (unsigned char*)take((size_t)N * DIM);         // 6.4 MB
  unsigned char*  g3f8 = (unsigned char*)take((size_t)N * DIM);         // 6.4 MB

  k_gemmbin<<<G + nblk, 512, 0, stream>>>(
      feat, W, bias, src, dst, g1b, g2f8, g3f8,
      scrF, scrB, offsF, offsB, N, E, G, nblk);
  k_csr<<<dim3(nbkt, 2), 512, 0, stream>>>(scrF, scrB, offsF, offsB,
                                           fnbr, bnbr, degF, degB, N, E, nblk);
  k_aggregate<<<(N + 3) / 4, 256, 0, stream>>>(g2f8, g3f8, g1b, degF, degB,
                                               fnbr, bnbr, out, N);
}